// Round 3
// baseline (4936.174 us; speedup 1.0000x reference)
//
#include <hip/hip_runtime.h>

// SAIGTransformer — dtype-robust round. Device-side detection of input dtype
// (f32 vs bf16), templated kernels launched in both flavors with uniform
// early-exit on a ws flag. Intermediates always bf16 in ws (~193 MiB used).

namespace {
constexpr int kB = 4;
constexpr int kC = 96;
constexpr int kHW = 65536;
constexpr int kNP = kB * kHW;       // 262144
constexpr int kQKVC = 288;
constexpr int kNH = 4;
constexpr int kCH = 24;
constexpr int kQC = 27;
constexpr int kHID = 255;
}

__device__ __forceinline__ float bf2f(unsigned short u) {
  return __uint_as_float(((unsigned int)u) << 16);
}
__device__ __forceinline__ unsigned short f2bf(float f) {
  unsigned int i = __float_as_uint(f);
  i += 0x7fffu + ((i >> 16) & 1u);
  return (unsigned short)(i >> 16);
}

// Input loader: F32 -> read as float; else read as bf16 bits.
template <bool F32>
__device__ __forceinline__ float ld(const void* p, size_t i) {
  if (F32) return ((const float*)p)[i];
  return bf2f(((const unsigned short*)p)[i]);
}

// ---- detect: bf16 N(0,1) never has exponent field >= 0x90; f32 low halves do ~44%.
__global__ void k_detect(const unsigned short* __restrict__ x, int* __restrict__ flag) {
  __shared__ int cnt;
  if (threadIdx.x == 0) cnt = 0;
  __syncthreads();
  int c = 0;
  for (int i = threadIdx.x; i < 4096; i += 256) {
    const unsigned int e = (x[i] >> 7) & 0xFF;
    if (e >= 0x90) ++c;
  }
  atomicAdd(&cnt, c);
  __syncthreads();
  if (threadIdx.x == 0) *flag = (cnt > 64) ? 1 : 0;
}

__global__ void k_zero(float* __restrict__ p, int n) {
  const int i = blockIdx.x * blockDim.x + threadIdx.x;
  if (i < n) p[i] = 0.f;
}

__global__ void k_fill0_us(unsigned short* __restrict__ p, int n) {
  const int i = blockIdx.x * blockDim.x + threadIdx.x;
  if (i < n) p[i] = 0;
}

// ---- K1: LN1 + 96-output slice of qkv -> buf (bf16) ----
template <bool F32>
__global__ __launch_bounds__(128) void k_ln_qkv(
    const void* __restrict__ x, const void* __restrict__ nw, const void* __restrict__ nb,
    const void* __restrict__ qkvw, int grp,
    unsigned short* __restrict__ buf, const int* __restrict__ flag) {
  if ((*flag != 0) != F32) return;
  __shared__ float xs[kC][128];
  const int tid = threadIdx.x;
  const int pg = blockIdx.x * 128 + tid;
  const int b = pg >> 16, p = pg & (kHW - 1);
  const size_t xbase = (size_t)b * kC * kHW + p;
  float s = 0.f, s2 = 0.f;
  for (int c = 0; c < kC; ++c) {
    const float v = ld<F32>(x, xbase + (size_t)c * kHW);
    xs[c][tid] = v; s += v; s2 += v * v;
  }
  const float mu = s * (1.f / kC);
  const float var = s2 * (1.f / kC) - mu * mu;
  const float rstd = rsqrtf(var + 1e-5f);
  for (int c = 0; c < kC; ++c)
    xs[c][tid] = (xs[c][tid] - mu) * rstd * ld<F32>(nw, c) + ld<F32>(nb, c);
  unsigned short* ob = buf + (size_t)b * kC * kHW + p;
  const size_t w0 = (size_t)grp * kC * kC;
  for (int og = 0; og < kC; og += 8) {
    float acc[8];
    #pragma unroll
    for (int j = 0; j < 8; ++j) acc[j] = 0.f;
    for (int c = 0; c < kC; c += 4) {
      const float x0 = xs[c][tid], x1 = xs[c + 1][tid];
      const float x2v = xs[c + 2][tid], x3 = xs[c + 3][tid];
      #pragma unroll
      for (int j = 0; j < 8; ++j) {
        const size_t r = w0 + (size_t)(og + j) * kC + c;
        acc[j] += ld<F32>(qkvw, r) * x0 + ld<F32>(qkvw, r + 1) * x1 +
                  ld<F32>(qkvw, r + 2) * x2v + ld<F32>(qkvw, r + 3) * x3;
      }
    }
    #pragma unroll
    for (int j = 0; j < 8; ++j) ob[(size_t)(og + j) * kHW] = f2bf(acc[j]);
  }
}

// ---- K2: depthwise 3x3 SAME on one 96-channel group ----
template <bool F32>
__global__ __launch_bounds__(256) void k_dw(
    const unsigned short* __restrict__ buf, const void* __restrict__ dww,
    unsigned short* __restrict__ qkv_post, int gbase, const int* __restrict__ flag) {
  if ((*flag != 0) != F32) return;
  const int row = blockIdx.x;
  const int y = row & 255;
  const int bcl = row >> 8;
  const int b = bcl / kC, chl = bcl % kC;
  const int tx = threadIdx.x;
  const unsigned short* in = buf + (size_t)bcl * kHW;
  float w[9];
  #pragma unroll
  for (int i = 0; i < 9; ++i) w[i] = ld<F32>(dww, (size_t)(gbase + chl) * 9 + i);
  float acc = 0.f;
  #pragma unroll
  for (int dy = -1; dy <= 1; ++dy) {
    const int yy = y + dy;
    if (yy < 0 || yy > 255) continue;
    #pragma unroll
    for (int dx = -1; dx <= 1; ++dx) {
      const int xx = tx + dx;
      if (xx < 0 || xx > 255) continue;
      acc += w[(dy + 1) * 3 + (dx + 1)] * bf2f(in[yy * 256 + xx]);
    }
  }
  qkv_post[((size_t)b * kQKVC + gbase + chl) * kHW + y * 256 + tx] = f2bf(acc);
}

// ---- K3: 1/max(||row||,eps): [0,384) q, [384,768) k, [768,816) svp ----
template <bool F32>
__global__ __launch_bounds__(256) void k_rnorm(
    const unsigned short* __restrict__ qkv_post, const void* __restrict__ svp,
    const void* __restrict__ svpw, float* __restrict__ rnorm,
    const int* __restrict__ flag) {
  if ((*flag != 0) != F32) return;
  const int row = blockIdx.x;
  const int tid = threadIdx.x;
  float ss = 0.f;
  if (row < 768) {
    const int which = row / 384;
    const int r = row % 384;
    const int b = r / kC, hc = r % kC;
    const unsigned short* base = qkv_post + ((size_t)b * kQKVC + which * kC + hc) * kHW;
    for (int i = tid; i < kHW; i += 256) { const float v = bf2f(base[i]); ss += v * v; }
  } else {
    const int r = row - 768;
    const int b = r / 12, j = r % 12;
    const float w0 = ld<F32>(svpw, j * 3 + 0);
    const float w1 = ld<F32>(svpw, j * 3 + 1);
    const float w2 = ld<F32>(svpw, j * 3 + 2);
    const size_t s0 = ((size_t)b * 3 + 0) * kHW;
    const size_t s1 = ((size_t)b * 3 + 1) * kHW;
    const size_t s2b = ((size_t)b * 3 + 2) * kHW;
    for (int i = tid; i < kHW; i += 256) {
      const float v = w0 * ld<F32>(svp, s0 + i) + w1 * ld<F32>(svp, s1 + i) +
                      w2 * ld<F32>(svp, s2b + i);
      ss += v * v;
    }
  }
  __shared__ float red[256];
  red[tid] = ss;
  __syncthreads();
  for (int s = 128; s > 0; s >>= 1) {
    if (tid < s) red[tid] += red[tid + s];
    __syncthreads();
  }
  if (tid == 0) rnorm[row] = 1.f / fmaxf(sqrtf(red[0]), 1e-12f);
}

// ---- K4: raw S = q_cat . k^T, atomic partials ----
template <bool F32>
__global__ __launch_bounds__(256) void k_qk(
    const unsigned short* __restrict__ qkv_post, const void* __restrict__ svp,
    const void* __restrict__ svpw, float* __restrict__ sraw,
    const int* __restrict__ flag) {
  if ((*flag != 0) != F32) return;
  const int bh = blockIdx.y;
  const int b = bh >> 2, h = bh & 3;
  const int tid = threadIdx.x;
  __shared__ float qs[kQC][65];
  __shared__ float ks[kCH][65];
  float acc0 = 0.f, acc1 = 0.f, acc2 = 0.f;
  const int p0 = blockIdx.x * 2048;
  for (int sub = 0; sub < 2048; sub += 64) {
    const int pb = p0 + sub;
    for (int idx = tid; idx < 51 * 64; idx += 256) {
      const int r = idx >> 6, e = idx & 63;
      if (r < 24) {
        qs[r][e] = bf2f(qkv_post[((size_t)b * kQKVC + h * kCH + r) * kHW + pb + e]);
      } else if (r < 27) {
        const int j = h * 3 + (r - 24);
        float a = 0.f;
        #pragma unroll
        for (int i = 0; i < 3; ++i)
          a += ld<F32>(svpw, j * 3 + i) * ld<F32>(svp, ((size_t)b * 3 + i) * kHW + pb + e);
        qs[r][e] = a;
      } else {
        ks[r - 27][e] = bf2f(qkv_post[((size_t)b * kQKVC + kC + h * kCH + (r - 27)) * kHW + pb + e]);
      }
    }
    __syncthreads();
    {
      int pair = tid;
      {
        const int cc = pair / 24, dd = pair - cc * 24;
        float a = 0.f;
        #pragma unroll 16
        for (int e = 0; e < 64; ++e) a += qs[cc][e] * ks[dd][e];
        acc0 += a;
      }
      pair = tid + 256;
      {
        const int cc = pair / 24, dd = pair - cc * 24;
        float a = 0.f;
        #pragma unroll 16
        for (int e = 0; e < 64; ++e) a += qs[cc][e] * ks[dd][e];
        acc1 += a;
      }
      pair = tid + 512;
      if (pair < 648) {
        const int cc = pair / 24, dd = pair - cc * 24;
        float a = 0.f;
        #pragma unroll 16
        for (int e = 0; e < 64; ++e) a += qs[cc][e] * ks[dd][e];
        acc2 += a;
      }
    }
    __syncthreads();
  }
  atomicAdd(&sraw[bh * 648 + tid], acc0);
  atomicAdd(&sraw[bh * 648 + tid + 256], acc1);
  if (tid + 512 < 648) atomicAdd(&sraw[bh * 648 + tid + 512], acc2);
}

// ---- K5: scale + softmax over 24 ----
template <bool F32>
__global__ __launch_bounds__(256) void k_softmax(
    const float* __restrict__ sraw, const float* __restrict__ rnorm,
    const void* __restrict__ temp, float* __restrict__ attn,
    const int* __restrict__ flag) {
  if ((*flag != 0) != F32) return;
  const int row = blockIdx.x * 256 + threadIdx.x;
  if (row >= kB * kNH * kQC) return;
  const int bh = row / kQC, c = row - bh * kQC;
  const int b = bh >> 2, h = bh & 3;
  const float rq = (c < kCH) ? rnorm[b * 96 + h * kCH + c]
                             : rnorm[768 + b * 12 + h * 3 + (c - kCH)];
  const float t = ld<F32>(temp, h);
  const float* srow = sraw + (size_t)(bh * kQC + c) * kCH;
  float l[kCH];
  float mx = -1e30f;
  #pragma unroll
  for (int d = 0; d < kCH; ++d) {
    const float rk = rnorm[384 + b * 96 + h * kCH + d];
    l[d] = srow[d] * rq * rk * t;
    mx = fmaxf(mx, l[d]);
  }
  float sum = 0.f;
  #pragma unroll
  for (int d = 0; d < kCH; ++d) { l[d] = __expf(l[d] - mx); sum += l[d]; }
  const float inv = 1.f / sum;
  float* arow = attn + (size_t)(bh * kQC + c) * kCH;
  #pragma unroll
  for (int d = 0; d < kCH; ++d) arow[d] = l[d] * inv;
}

// ---- K6: attn @ v -> dead q/k planes (b*288 + h*27+c); no external inputs ----
__global__ __launch_bounds__(256) void k_av(
    const float* __restrict__ attn, unsigned short* __restrict__ qkv_post) {
  const int h = blockIdx.y;
  const int pg = blockIdx.x * 256 + threadIdx.x;
  const int b = pg >> 16, p = pg & (kHW - 1);
  __shared__ float at[kQC * kCH];
  for (int idx = threadIdx.x; idx < kQC * kCH; idx += 256)
    at[idx] = attn[(size_t)(b * kNH + h) * kQC * kCH + idx];
  __syncthreads();
  float acc[kQC];
  #pragma unroll
  for (int c = 0; c < kQC; ++c) acc[c] = 0.f;
  for (int d = 0; d < kCH; ++d) {
    const float vv = bf2f(qkv_post[((size_t)b * kQKVC + 192 + h * kCH + d) * kHW + p]);
    #pragma unroll
    for (int c = 0; c < kQC; ++c) acc[c] += at[c * kCH + d] * vv;
  }
  #pragma unroll
  for (int c = 0; c < kQC; ++c)
    qkv_post[((size_t)b * kQKVC + h * kQC + c) * kHW + p] = f2bf(acc[c]);
}

// ---- K7: x2 = x + proj_out_w @ out (bf16 x2) ----
template <bool F32>
__global__ __launch_bounds__(128) void k_proj(
    const unsigned short* __restrict__ qkv_post, const void* __restrict__ x,
    const void* __restrict__ projw, unsigned short* __restrict__ x2,
    const int* __restrict__ flag) {
  if ((*flag != 0) != F32) return;
  __shared__ float os[108][128];
  const int tid = threadIdx.x;
  const int pg0 = blockIdx.x * 128;
  const int b = pg0 >> 16, p0 = pg0 & (kHW - 1);
  for (int idx = tid; idx < 108 * 128; idx += 128) {
    const int j = idx >> 7, e = idx & 127;
    os[j][e] = bf2f(qkv_post[((size_t)b * kQKVC + j) * kHW + p0 + e]);
  }
  __syncthreads();
  const int p = p0 + tid;
  for (int og = 0; og < kC; og += 8) {
    float acc[8];
    #pragma unroll
    for (int j = 0; j < 8; ++j) acc[j] = 0.f;
    for (int c = 0; c < 108; c += 4) {
      const float y0 = os[c][tid], y1 = os[c + 1][tid];
      const float y2 = os[c + 2][tid], y3 = os[c + 3][tid];
      #pragma unroll
      for (int j = 0; j < 8; ++j) {
        const size_t r = (size_t)(og + j) * 108 + c;
        acc[j] += ld<F32>(projw, r) * y0 + ld<F32>(projw, r + 1) * y1 +
                  ld<F32>(projw, r + 2) * y2 + ld<F32>(projw, r + 3) * y3;
      }
    }
    #pragma unroll
    for (int j = 0; j < 8; ++j) {
      const float v = acc[j] + ld<F32>(x, ((size_t)b * kC + og + j) * kHW + p);
      x2[((size_t)b * kC + og + j) * kHW + p] = f2bf(v);
    }
  }
}

// ---- K8: LN2 + dual gate -> g (bf16) ----
template <bool F32>
__global__ __launch_bounds__(128) void k_ffn_gate(
    const unsigned short* __restrict__ x2, const void* __restrict__ nw,
    const void* __restrict__ nb, const void* __restrict__ w1,
    const void* __restrict__ w2, unsigned short* __restrict__ g,
    const int* __restrict__ flag) {
  if ((*flag != 0) != F32) return;
  __shared__ float xs[kC][128];
  const int tid = threadIdx.x;
  const int pg = blockIdx.x * 128 + tid;
  const int b = pg >> 16, p = pg & (kHW - 1);
  float s = 0.f, s2 = 0.f;
  for (int c = 0; c < kC; ++c) {
    const float v = bf2f(x2[((size_t)b * kC + c) * kHW + p]);
    xs[c][tid] = v; s += v; s2 += v * v;
  }
  const float m = s * (1.f / kC);
  const float var = s2 * (1.f / kC) - m * m;
  const float rstd = rsqrtf(var + 1e-5f);
  for (int c = 0; c < kC; ++c)
    xs[c][tid] = (xs[c][tid] - m) * rstd * ld<F32>(nw, c) + ld<F32>(nb, c);
  for (int i = 0; i < kHID; i += 5) {
    float a1[5], a2[5];
    #pragma unroll
    for (int q = 0; q < 5; ++q) { a1[q] = 0.f; a2[q] = 0.f; }
    for (int c = 0; c < kC; c += 4) {
      const float x0 = xs[c][tid], x1 = xs[c + 1][tid];
      const float x2v = xs[c + 2][tid], x3 = xs[c + 3][tid];
      #pragma unroll
      for (int q = 0; q < 5; ++q) {
        const size_t r = (size_t)(i + q) * kC + c;
        a1[q] += ld<F32>(w1, r) * x0 + ld<F32>(w1, r + 1) * x1 +
                 ld<F32>(w1, r + 2) * x2v + ld<F32>(w1, r + 3) * x3;
        a2[q] += ld<F32>(w2, r) * x0 + ld<F32>(w2, r + 1) * x1 +
                 ld<F32>(w2, r + 2) * x2v + ld<F32>(w2, r + 3) * x3;
      }
    }
    #pragma unroll
    for (int q = 0; q < 5; ++q) {
      const float p1 = a1[q], p2 = a2[q];
      const float sig = 1.f / (1.f + __expf(-p2));
      const float gel = 0.5f * p1 * (1.f + erff(p1 * 0.70710678118f));
      g[((size_t)b * kHID + i + q) * kHW + p] = f2bf(p1 * sig + p2 * gel);
    }
  }
}

// ---- K9: out = x2 + ffn_out_w @ g (dtype-matched store, NaN sentinel) ----
template <bool F32>
__global__ __launch_bounds__(128) void k_ffn_out(
    const unsigned short* __restrict__ g, const unsigned short* __restrict__ x2,
    const void* __restrict__ fw, void* __restrict__ out,
    const int* __restrict__ flag) {
  if ((*flag != 0) != F32) return;
  __shared__ unsigned short gs[kHID][128];
  const int tid = threadIdx.x;
  const int pg0 = blockIdx.x * 128;
  const int b = pg0 >> 16, p0 = pg0 & (kHW - 1);
  for (int idx = tid; idx < kHID * 128; idx += 128) {
    const int j = idx >> 7, e = idx & 127;
    gs[j][e] = g[((size_t)b * kHID + j) * kHW + p0 + e];
  }
  __syncthreads();
  const int p = p0 + tid;
  for (int og = 0; og < kC; og += 8) {
    float acc[8];
    #pragma unroll
    for (int j = 0; j < 8; ++j) acc[j] = 0.f;
    for (int c = 0; c < kHID; ++c) {
      const float xv = bf2f(gs[c][tid]);
      #pragma unroll
      for (int j = 0; j < 8; ++j)
        acc[j] += ld<F32>(fw, (size_t)(og + j) * kHID + c) * xv;
    }
    #pragma unroll
    for (int j = 0; j < 8; ++j) {
      float v = acc[j] + bf2f(x2[((size_t)b * kC + og + j) * kHW + p]);
      if (!(fabsf(v) < 1e30f)) v = 1000.0f;   // NaN/Inf sentinel (diagnostic)
      const size_t oi = ((size_t)b * kC + og + j) * kHW + p;
      if (F32) ((float*)out)[oi] = v;
      else ((unsigned short*)out)[oi] = f2bf(v);
    }
  }
}

extern "C" void kernel_launch(void* const* d_in, const int* in_sizes, int n_in,
                              void* d_out, int out_size, void* d_ws, size_t ws_size,
                              hipStream_t stream) {
  (void)in_sizes; (void)n_in;
  const void* x     = d_in[0];
  const void* svp   = d_in[1];
  const void* n1w   = d_in[2];
  const void* n1b   = d_in[3];
  const void* qkvw  = d_in[4];
  const void* dww   = d_in[5];
  const void* svpw  = d_in[6];
  const void* temp  = d_in[7];
  const void* projw = d_in[8];
  const void* n2w   = d_in[9];
  const void* n2b   = d_in[10];
  const void* w1    = d_in[11];
  const void* w2    = d_in[12];
  const void* fw    = d_in[13];

  const size_t SZ_A = (size_t)kB * kQKVC * kHW * 2;   // 150,994,944
  const size_t SZ_C = (size_t)kB * kC * kHW * 2;      //  50,331,648
  const size_t NEED = (1u << 20) + SZ_A + SZ_C;       // ~193 MiB + 1 MiB

  if (ws_size < NEED) {
    k_fill0_us<<<(out_size + 255) / 256, 256, 0, stream>>>((unsigned short*)d_out, out_size);
    return;
  }

  char* ws = (char*)d_ws;
  float* sraw  = (float*)(ws);                 // 41,472 B
  float* attn  = (float*)(ws + 65536);         // 41,472 B
  float* rnorm = (float*)(ws + 131072);        // 3,264 B
  int*   flag  = (int*)(ws + 196608);
  unsigned short* qkv_post = (unsigned short*)(ws + (1u << 20));
  unsigned short* bufC     = (unsigned short*)(ws + (1u << 20) + SZ_A);
  unsigned short* x2       = bufC;
  unsigned short* g        = qkv_post;

  k_detect<<<1, 256, 0, stream>>>((const unsigned short*)x, flag);
  k_zero<<<(16 * 648 + 255) / 256, 256, 0, stream>>>(sraw, 16 * 648);

  for (int grp = 0; grp < 3; ++grp) {
    k_ln_qkv<false><<<kNP / 128, 128, 0, stream>>>(x, n1w, n1b, qkvw, grp, bufC, flag);
    k_ln_qkv<true ><<<kNP / 128, 128, 0, stream>>>(x, n1w, n1b, qkvw, grp, bufC, flag);
    k_dw<false><<<kB * kC * 256, 256, 0, stream>>>(bufC, dww, qkv_post, grp * kC, flag);
    k_dw<true ><<<kB * kC * 256, 256, 0, stream>>>(bufC, dww, qkv_post, grp * kC, flag);
  }
  k_rnorm<false><<<816, 256, 0, stream>>>(qkv_post, svp, svpw, rnorm, flag);
  k_rnorm<true ><<<816, 256, 0, stream>>>(qkv_post, svp, svpw, rnorm, flag);
  k_qk<false><<<dim3(32, 16), 256, 0, stream>>>(qkv_post, svp, svpw, sraw, flag);
  k_qk<true ><<<dim3(32, 16), 256, 0, stream>>>(qkv_post, svp, svpw, sraw, flag);
  k_softmax<false><<<2, 256, 0, stream>>>(sraw, rnorm, temp, attn, flag);
  k_softmax<true ><<<2, 256, 0, stream>>>(sraw, rnorm, temp, attn, flag);
  k_av<<<dim3(kNP / 256, kNH), 256, 0, stream>>>(attn, qkv_post);
  k_proj<false><<<kNP / 128, 128, 0, stream>>>(qkv_post, x, projw, x2, flag);
  k_proj<true ><<<kNP / 128, 128, 0, stream>>>(qkv_post, x, projw, x2, flag);
  k_ffn_gate<false><<<kNP / 128, 128, 0, stream>>>(x2, n2w, n2b, w1, w2, g, flag);
  k_ffn_gate<true ><<<kNP / 128, 128, 0, stream>>>(x2, n2w, n2b, w1, w2, g, flag);
  k_ffn_out<false><<<kNP / 128, 128, 0, stream>>>(g, x2, fw, d_out, flag);
  k_ffn_out<true ><<<kNP / 128, 128, 0, stream>>>(g, x2, fw, d_out, flag);
}

// Round 4
// 1665.006 us; speedup vs baseline: 2.9647x; 2.9647x over previous
//
#include <hip/hip_runtime.h>

// SAIGTransformer (f32 in/out, bf16 intermediates + MFMA GEMMs).
// ws layout (NEED = 202,375,168 B, proven in R3):
//   [0,1MB): sraw/attn/rnorm smalls
//   A @1MB, 151MB: qkv_post(288 planes bf16) -> g(255 planes) ; LN1 stats in last
//     2MB (dead before dw of group 2 overwrites); LN2 stats @A+134MB (after proj)
//   C @1MB+151MB, 48MB: per-group qkv GEMM out -> x2 (bf16)

namespace {
constexpr int kB = 4;
constexpr int kC = 96;
constexpr int kHW = 65536;
constexpr int kNP = kB * kHW;
constexpr int kQKVC = 288;
constexpr int kNH = 4;
constexpr int kCH = 24;
constexpr int kQC = 27;
constexpr int kHID = 255;
constexpr int kSTR = 40;   // LDS k-stride: 32+8 pad, rows 80B (16B-aligned, 2-way max)
}

typedef __attribute__((ext_vector_type(8))) short short8;
typedef __attribute__((ext_vector_type(8))) unsigned short ushort8;
typedef __attribute__((ext_vector_type(4))) float floatx4;

__device__ __forceinline__ float bf2f(unsigned short u) {
  return __uint_as_float(((unsigned int)u) << 16);
}
__device__ __forceinline__ unsigned short f2bf(float f) {
  unsigned int i = __float_as_uint(f);
  i += 0x7fffu + ((i >> 16) & 1u);
  return (unsigned short)(i >> 16);
}

__global__ void k_zero(float* __restrict__ p, int n) {
  const int i = blockIdx.x * blockDim.x + threadIdx.x;
  if (i < n) p[i] = 0.f;
}
__global__ void k_fill0_f32(float* __restrict__ p, int n) {
  const int i = blockIdx.x * blockDim.x + threadIdx.x;
  if (i < n) p[i] = 0.f;
}

// ---- LN stats (f32 input) -> mu, rstd per pixel ----
__global__ __launch_bounds__(256) void k_ln1_stats(
    const float* __restrict__ x, float* __restrict__ mu, float* __restrict__ rs) {
  const int pg = blockIdx.x * 256 + threadIdx.x;
  const int b = pg >> 16, p = pg & (kHW - 1);
  const float* xb = x + (size_t)b * kC * kHW + p;
  float s = 0.f, s2 = 0.f;
  for (int c = 0; c < kC; ++c) { const float v = xb[(size_t)c * kHW]; s += v; s2 += v * v; }
  const float m = s * (1.f / kC);
  const float var = s2 * (1.f / kC) - m * m;
  mu[pg] = m;
  rs[pg] = rsqrtf(var + 1e-5f);
}

// ---- LN stats (bf16 input x2) ----
__global__ __launch_bounds__(256) void k_ln2_stats(
    const unsigned short* __restrict__ x2, float* __restrict__ mu, float* __restrict__ rs) {
  const int pg = blockIdx.x * 256 + threadIdx.x;
  const int b = pg >> 16, p = pg & (kHW - 1);
  const unsigned short* xb = x2 + (size_t)b * kC * kHW + p;
  float s = 0.f, s2 = 0.f;
  for (int c = 0; c < kC; ++c) { const float v = bf2f(xb[(size_t)c * kHW]); s += v; s2 += v * v; }
  const float m = s * (1.f / kC);
  const float var = s2 * (1.f / kC) - m * m;
  mu[pg] = m;
  rs[pg] = rsqrtf(var + 1e-5f);
}

// ==== GEMM 1: qkv group (M=96, K=96), B = LN1(x) fused in staging ====
__global__ __launch_bounds__(256) void k_gemm_qkv(
    const float* __restrict__ x, const float* __restrict__ mu_buf,
    const float* __restrict__ rs_buf, const float* __restrict__ nw,
    const float* __restrict__ nb, const float* __restrict__ qkvw, int grp,
    unsigned short* __restrict__ bufC) {
  __shared__ __align__(16) unsigned short As[96 * kSTR];
  __shared__ __align__(16) unsigned short Bs[128 * kSTR];
  __shared__ float mus[128], rss[128];
  const int tid = threadIdx.x;
  const int b = blockIdx.y;
  const int p0 = blockIdx.x * 128;
  if (tid < 128) {
    mus[tid] = mu_buf[(b << 16) + p0 + tid];
    rss[tid] = rs_buf[(b << 16) + p0 + tid];
  }
  const int wave = tid >> 6, lane = tid & 63, ln16 = lane & 15, quad = lane >> 4;
  floatx4 acc[6][2];
  #pragma unroll
  for (int i = 0; i < 6; ++i)
    #pragma unroll
    for (int j = 0; j < 2; ++j) acc[i][j] = (floatx4)(0.f);
  __syncthreads();
  const int rB = tid >> 3, c0 = (tid & 7) * 16;
  for (int ks = 0; ks < 3; ++ks) {
    const int k0 = ks * 32;
    for (int i = tid; i < 96 * 32; i += 256) {
      const int m = i >> 5, kk = i & 31;
      As[m * kSTR + kk] = f2bf(qkvw[(size_t)(grp * 96 + m) * 96 + k0 + kk]);
    }
    {
      const int k = k0 + rB;
      const float wk = nw[k], bk = nb[k];
      const float* src = x + ((size_t)b * kC + k) * kHW + p0 + c0;
      float tmp[16];
      #pragma unroll
      for (int q = 0; q < 4; ++q) {
        const floatx4 v = ((const floatx4*)src)[q];
        #pragma unroll
        for (int e = 0; e < 4; ++e) tmp[q * 4 + e] = v[e];
      }
      #pragma unroll
      for (int e = 0; e < 16; ++e) {
        const int n = c0 + e;
        Bs[n * kSTR + rB] = f2bf((tmp[e] - mus[n]) * rss[n] * wk + bk);
      }
    }
    __syncthreads();
    short8 bfr0 = *(const short8*)&Bs[(wave * 32 + ln16) * kSTR + quad * 8];
    short8 bfr1 = *(const short8*)&Bs[(wave * 32 + 16 + ln16) * kSTR + quad * 8];
    #pragma unroll
    for (int ms = 0; ms < 6; ++ms) {
      const short8 afr = *(const short8*)&As[(ms * 16 + ln16) * kSTR + quad * 8];
      acc[ms][0] = __builtin_amdgcn_mfma_f32_16x16x32_bf16(afr, bfr0, acc[ms][0], 0, 0, 0);
      acc[ms][1] = __builtin_amdgcn_mfma_f32_16x16x32_bf16(afr, bfr1, acc[ms][1], 0, 0, 0);
    }
    __syncthreads();
  }
  unsigned short* ob = bufC + (size_t)b * kC * kHW;
  #pragma unroll
  for (int ms = 0; ms < 6; ++ms)
    #pragma unroll
    for (int ns = 0; ns < 2; ++ns)
      #pragma unroll
      for (int r = 0; r < 4; ++r) {
        const int R = ms * 16 + quad * 4 + r;
        const int P = p0 + wave * 32 + ns * 16 + ln16;
        ob[(size_t)R * kHW + P] = f2bf(acc[ms][ns][r]);
      }
}

// ==== GEMM 2: proj (M=96, K=108 pad 128), B = out planes, + x residual ====
__global__ __launch_bounds__(256) void k_gemm_proj(
    const unsigned short* __restrict__ qkv_post, const float* __restrict__ projw,
    const float* __restrict__ x, unsigned short* __restrict__ x2) {
  __shared__ __align__(16) unsigned short As[96 * kSTR];
  __shared__ __align__(16) unsigned short Bs[128 * kSTR];
  const int tid = threadIdx.x;
  const int b = blockIdx.y;
  const int p0 = blockIdx.x * 128;
  const int wave = tid >> 6, lane = tid & 63, ln16 = lane & 15, quad = lane >> 4;
  floatx4 acc[6][2];
  #pragma unroll
  for (int i = 0; i < 6; ++i)
    #pragma unroll
    for (int j = 0; j < 2; ++j) acc[i][j] = (floatx4)(0.f);
  const int rB = tid >> 3, c0 = (tid & 7) * 16;
  for (int ks = 0; ks < 4; ++ks) {
    const int k0 = ks * 32;
    for (int i = tid; i < 96 * 32; i += 256) {
      const int m = i >> 5, kk = i & 31;
      const int k = k0 + kk;
      As[m * kSTR + kk] = (k < 108) ? f2bf(projw[(size_t)m * 108 + k]) : (unsigned short)0;
    }
    {
      const int k = k0 + rB;
      if (k < 108) {
        const unsigned short* src = qkv_post + ((size_t)b * kQKVC + k) * kHW + p0 + c0;
        const ushort8 u0 = ((const ushort8*)src)[0];
        const ushort8 u1 = ((const ushort8*)src)[1];
        #pragma unroll
        for (int e = 0; e < 8; ++e) {
          Bs[(c0 + e) * kSTR + rB] = u0[e];
          Bs[(c0 + 8 + e) * kSTR + rB] = u1[e];
        }
      } else {
        #pragma unroll
        for (int e = 0; e < 16; ++e) Bs[(c0 + e) * kSTR + rB] = 0;
      }
    }
    __syncthreads();
    short8 bfr0 = *(const short8*)&Bs[(wave * 32 + ln16) * kSTR + quad * 8];
    short8 bfr1 = *(const short8*)&Bs[(wave * 32 + 16 + ln16) * kSTR + quad * 8];
    #pragma unroll
    for (int ms = 0; ms < 6; ++ms) {
      const short8 afr = *(const short8*)&As[(ms * 16 + ln16) * kSTR + quad * 8];
      acc[ms][0] = __builtin_amdgcn_mfma_f32_16x16x32_bf16(afr, bfr0, acc[ms][0], 0, 0, 0);
      acc[ms][1] = __builtin_amdgcn_mfma_f32_16x16x32_bf16(afr, bfr1, acc[ms][1], 0, 0, 0);
    }
    __syncthreads();
  }
  #pragma unroll
  for (int ms = 0; ms < 6; ++ms)
    #pragma unroll
    for (int ns = 0; ns < 2; ++ns)
      #pragma unroll
      for (int r = 0; r < 4; ++r) {
        const int R = ms * 16 + quad * 4 + r;
        const int P = p0 + wave * 32 + ns * 16 + ln16;
        const size_t idx = ((size_t)b * kC + R) * kHW + P;
        x2[idx] = f2bf(acc[ms][ns][r] + x[idx]);
      }
}

// ==== GEMM 3: ffn gate (M=128: 64 W1-rows + 64 W2-rows, K=96), LN2 fused ====
__global__ __launch_bounds__(256) void k_gemm_gate(
    const unsigned short* __restrict__ x2, const float* __restrict__ mu_buf,
    const float* __restrict__ rs_buf, const float* __restrict__ nw,
    const float* __restrict__ nb, const float* __restrict__ w1,
    const float* __restrict__ w2, unsigned short* __restrict__ g) {
  __shared__ __align__(16) unsigned short As[128 * kSTR];
  __shared__ __align__(16) unsigned short Bs[128 * kSTR];
  __shared__ float mus[128], rss[128];
  const int tid = threadIdx.x;
  const int i0 = blockIdx.y * 64;
  const int b = blockIdx.z;
  const int p0 = blockIdx.x * 128;
  if (tid < 128) {
    mus[tid] = mu_buf[(b << 16) + p0 + tid];
    rss[tid] = rs_buf[(b << 16) + p0 + tid];
  }
  const int wave = tid >> 6, lane = tid & 63, ln16 = lane & 15, quad = lane >> 4;
  floatx4 acc[8][2];
  #pragma unroll
  for (int i = 0; i < 8; ++i)
    #pragma unroll
    for (int j = 0; j < 2; ++j) acc[i][j] = (floatx4)(0.f);
  __syncthreads();
  const int rB = tid >> 3, c0 = (tid & 7) * 16;
  for (int ks = 0; ks < 3; ++ks) {
    const int k0 = ks * 32;
    for (int i = tid; i < 128 * 32; i += 256) {
      const int m = i >> 5, kk = i & 31;
      const int ii = i0 + (m & 63);
      float v = 0.f;
      if (ii < kHID) {
        v = (m < 64) ? w1[(size_t)ii * kC + k0 + kk] : w2[(size_t)ii * kC + k0 + kk];
      }
      As[m * kSTR + kk] = f2bf(v);
    }
    {
      const int k = k0 + rB;
      const float wk = nw[k], bk = nb[k];
      const unsigned short* src = x2 + ((size_t)b * kC + k) * kHW + p0 + c0;
      const ushort8 u0 = ((const ushort8*)src)[0];
      const ushort8 u1 = ((const ushort8*)src)[1];
      #pragma unroll
      for (int e = 0; e < 8; ++e) {
        const int n0 = c0 + e, n1 = c0 + 8 + e;
        Bs[n0 * kSTR + rB] = f2bf((bf2f(u0[e]) - mus[n0]) * rss[n0] * wk + bk);
        Bs[n1 * kSTR + rB] = f2bf((bf2f(u1[e]) - mus[n1]) * rss[n1] * wk + bk);
      }
    }
    __syncthreads();
    short8 bfr0 = *(const short8*)&Bs[(wave * 32 + ln16) * kSTR + quad * 8];
    short8 bfr1 = *(const short8*)&Bs[(wave * 32 + 16 + ln16) * kSTR + quad * 8];
    #pragma unroll
    for (int ms = 0; ms < 8; ++ms) {
      const short8 afr = *(const short8*)&As[(ms * 16 + ln16) * kSTR + quad * 8];
      acc[ms][0] = __builtin_amdgcn_mfma_f32_16x16x32_bf16(afr, bfr0, acc[ms][0], 0, 0, 0);
      acc[ms][1] = __builtin_amdgcn_mfma_f32_16x16x32_bf16(afr, bfr1, acc[ms][1], 0, 0, 0);
    }
    __syncthreads();
  }
  // gate: ms(0..3) = p1 rows i0+ms*16+..., ms+4 = matching p2 rows
  #pragma unroll
  for (int ms = 0; ms < 4; ++ms)
    #pragma unroll
    for (int ns = 0; ns < 2; ++ns)
      #pragma unroll
      for (int r = 0; r < 4; ++r) {
        const int ii = i0 + ms * 16 + quad * 4 + r;
        if (ii < kHID) {
          const int P = p0 + wave * 32 + ns * 16 + ln16;
          const float p1 = acc[ms][ns][r], p2 = acc[ms + 4][ns][r];
          const float sig = 1.f / (1.f + __expf(-p2));
          const float gel = 0.5f * p1 * (1.f + erff(p1 * 0.70710678118f));
          g[((size_t)b * kHID + ii) * kHW + P] = f2bf(p1 * sig + p2 * gel);
        }
      }
}

// ==== GEMM 4: ffn out (M=96, K=255 pad 256), + x2 residual, f32 out ====
__global__ __launch_bounds__(256) void k_gemm_fout(
    const unsigned short* __restrict__ g, const float* __restrict__ fw,
    const unsigned short* __restrict__ x2, float* __restrict__ out) {
  __shared__ __align__(16) unsigned short As[96 * kSTR];
  __shared__ __align__(16) unsigned short Bs[128 * kSTR];
  const int tid = threadIdx.x;
  const int b = blockIdx.y;
  const int p0 = blockIdx.x * 128;
  const int wave = tid >> 6, lane = tid & 63, ln16 = lane & 15, quad = lane >> 4;
  floatx4 acc[6][2];
  #pragma unroll
  for (int i = 0; i < 6; ++i)
    #pragma unroll
    for (int j = 0; j < 2; ++j) acc[i][j] = (floatx4)(0.f);
  const int rB = tid >> 3, c0 = (tid & 7) * 16;
  for (int ks = 0; ks < 8; ++ks) {
    const int k0 = ks * 32;
    for (int i = tid; i < 96 * 32; i += 256) {
      const int m = i >> 5, kk = i & 31;
      const int k = k0 + kk;
      As[m * kSTR + kk] = (k < kHID) ? f2bf(fw[(size_t)m * kHID + k]) : (unsigned short)0;
    }
    {
      const int k = k0 + rB;
      if (k < kHID) {
        const unsigned short* src = g + ((size_t)b * kHID + k) * kHW + p0 + c0;
        const ushort8 u0 = ((const ushort8*)src)[0];
        const ushort8 u1 = ((const ushort8*)src)[1];
        #pragma unroll
        for (int e = 0; e < 8; ++e) {
          Bs[(c0 + e) * kSTR + rB] = u0[e];
          Bs[(c0 + 8 + e) * kSTR + rB] = u1[e];
        }
      } else {
        #pragma unroll
        for (int e = 0; e < 16; ++e) Bs[(c0 + e) * kSTR + rB] = 0;
      }
    }
    __syncthreads();
    short8 bfr0 = *(const short8*)&Bs[(wave * 32 + ln16) * kSTR + quad * 8];
    short8 bfr1 = *(const short8*)&Bs[(wave * 32 + 16 + ln16) * kSTR + quad * 8];
    #pragma unroll
    for (int ms = 0; ms < 6; ++ms) {
      const short8 afr = *(const short8*)&As[(ms * 16 + ln16) * kSTR + quad * 8];
      acc[ms][0] = __builtin_amdgcn_mfma_f32_16x16x32_bf16(afr, bfr0, acc[ms][0], 0, 0, 0);
      acc[ms][1] = __builtin_amdgcn_mfma_f32_16x16x32_bf16(afr, bfr1, acc[ms][1], 0, 0, 0);
    }
    __syncthreads();
  }
  #pragma unroll
  for (int ms = 0; ms < 6; ++ms)
    #pragma unroll
    for (int ns = 0; ns < 2; ++ns)
      #pragma unroll
      for (int r = 0; r < 4; ++r) {
        const int R = ms * 16 + quad * 4 + r;
        const int P = p0 + wave * 32 + ns * 16 + ln16;
        const size_t idx = ((size_t)b * kC + R) * kHW + P;
        out[idx] = acc[ms][ns][r] + bf2f(x2[idx]);
      }
}

// ---- depthwise 3x3 SAME on one 96-channel group ----
__global__ __launch_bounds__(256) void k_dw(
    const unsigned short* __restrict__ buf, const float* __restrict__ dww,
    unsigned short* __restrict__ qkv_post, int gbase) {
  const int row = blockIdx.x;
  const int y = row & 255;
  const int bcl = row >> 8;
  const int b = bcl / kC, chl = bcl % kC;
  const int tx = threadIdx.x;
  const unsigned short* in = buf + (size_t)bcl * kHW;
  float w[9];
  #pragma unroll
  for (int i = 0; i < 9; ++i) w[i] = dww[(size_t)(gbase + chl) * 9 + i];
  float acc = 0.f;
  #pragma unroll
  for (int dy = -1; dy <= 1; ++dy) {
    const int yy = y + dy;
    if (yy < 0 || yy > 255) continue;
    #pragma unroll
    for (int dx = -1; dx <= 1; ++dx) {
      const int xx = tx + dx;
      if (xx < 0 || xx > 255) continue;
      acc += w[(dy + 1) * 3 + (dx + 1)] * bf2f(in[yy * 256 + xx]);
    }
  }
  qkv_post[((size_t)b * kQKVC + gbase + chl) * kHW + y * 256 + tx] = f2bf(acc);
}

// ---- 1/max(||row||,eps): [0,384) q, [384,768) k, [768,816) svp ----
__global__ __launch_bounds__(256) void k_rnorm(
    const unsigned short* __restrict__ qkv_post, const float* __restrict__ svp,
    const float* __restrict__ svpw, float* __restrict__ rnorm) {
  const int row = blockIdx.x;
  const int tid = threadIdx.x;
  float ss = 0.f;
  if (row < 768) {
    const int which = row / 384;
    const int r = row % 384;
    const int b = r / kC, hc = r % kC;
    const unsigned short* base = qkv_post + ((size_t)b * kQKVC + which * kC + hc) * kHW;
    for (int i = tid; i < kHW; i += 256) { const float v = bf2f(base[i]); ss += v * v; }
  } else {
    const int r = row - 768;
    const int b = r / 12, j = r % 12;
    const float w0 = svpw[j * 3 + 0], w1 = svpw[j * 3 + 1], w2 = svpw[j * 3 + 2];
    const float* s0 = svp + ((size_t)b * 3 + 0) * kHW;
    const float* s1 = svp + ((size_t)b * 3 + 1) * kHW;
    const float* s2 = svp + ((size_t)b * 3 + 2) * kHW;
    for (int i = tid; i < kHW; i += 256) {
      const float v = w0 * s0[i] + w1 * s1[i] + w2 * s2[i];
      ss += v * v;
    }
  }
  __shared__ float red[256];
  red[tid] = ss;
  __syncthreads();
  for (int s = 128; s > 0; s >>= 1) {
    if (tid < s) red[tid] += red[tid + s];
    __syncthreads();
  }
  if (tid == 0) rnorm[row] = 1.f / fmaxf(sqrtf(red[0]), 1e-12f);
}

// ---- raw S = q_cat . k^T, atomic partials ----
__global__ __launch_bounds__(256) void k_qk(
    const unsigned short* __restrict__ qkv_post, const float* __restrict__ svp,
    const float* __restrict__ svpw, float* __restrict__ sraw) {
  const int bh = blockIdx.y;
  const int b = bh >> 2, h = bh & 3;
  const int tid = threadIdx.x;
  __shared__ float qs[kQC][65];
  __shared__ float ks[kCH][65];
  float acc0 = 0.f, acc1 = 0.f, acc2 = 0.f;
  const int p0 = blockIdx.x * 2048;
  for (int sub = 0; sub < 2048; sub += 64) {
    const int pb = p0 + sub;
    for (int idx = tid; idx < 51 * 64; idx += 256) {
      const int r = idx >> 6, e = idx & 63;
      if (r < 24) {
        qs[r][e] = bf2f(qkv_post[((size_t)b * kQKVC + h * kCH + r) * kHW + pb + e]);
      } else if (r < 27) {
        const int j = h * 3 + (r - 24);
        float a = 0.f;
        #pragma unroll
        for (int i = 0; i < 3; ++i)
          a += svpw[j * 3 + i] * svp[((size_t)b * 3 + i) * kHW + pb + e];
        qs[r][e] = a;
      } else {
        ks[r - 27][e] = bf2f(qkv_post[((size_t)b * kQKVC + kC + h * kCH + (r - 27)) * kHW + pb + e]);
      }
    }
    __syncthreads();
    {
      int pair = tid;
      {
        const int cc = pair / 24, dd = pair - cc * 24;
        float a = 0.f;
        #pragma unroll 16
        for (int e = 0; e < 64; ++e) a += qs[cc][e] * ks[dd][e];
        acc0 += a;
      }
      pair = tid + 256;
      {
        const int cc = pair / 24, dd = pair - cc * 24;
        float a = 0.f;
        #pragma unroll 16
        for (int e = 0; e < 64; ++e) a += qs[cc][e] * ks[dd][e];
        acc1 += a;
      }
      pair = tid + 512;
      if (pair < 648) {
        const int cc = pair / 24, dd = pair - cc * 24;
        float a = 0.f;
        #pragma unroll 16
        for (int e = 0; e < 64; ++e) a += qs[cc][e] * ks[dd][e];
        acc2 += a;
      }
    }
    __syncthreads();
  }
  atomicAdd(&sraw[bh * 648 + tid], acc0);
  atomicAdd(&sraw[bh * 648 + tid + 256], acc1);
  if (tid + 512 < 648) atomicAdd(&sraw[bh * 648 + tid + 512], acc2);
}

// ---- scale + softmax over 24 ----
__global__ __launch_bounds__(256) void k_softmax(
    const float* __restrict__ sraw, const float* __restrict__ rnorm,
    const float* __restrict__ temp, float* __restrict__ attn) {
  const int row = blockIdx.x * 256 + threadIdx.x;
  if (row >= kB * kNH * kQC) return;
  const int bh = row / kQC, c = row - bh * kQC;
  const int b = bh >> 2, h = bh & 3;
  const float rq = (c < kCH) ? rnorm[b * 96 + h * kCH + c]
                             : rnorm[768 + b * 12 + h * 3 + (c - kCH)];
  const float t = temp[h];
  const float* srow = sraw + (size_t)(bh * kQC + c) * kCH;
  float l[kCH];
  float mx = -1e30f;
  #pragma unroll
  for (int d = 0; d < kCH; ++d) {
    const float rk = rnorm[384 + b * 96 + h * kCH + d];
    l[d] = srow[d] * rq * rk * t;
    mx = fmaxf(mx, l[d]);
  }
  float sum = 0.f;
  #pragma unroll
  for (int d = 0; d < kCH; ++d) { l[d] = __expf(l[d] - mx); sum += l[d]; }
  const float inv = 1.f / sum;
  float* arow = attn + (size_t)(bh * kQC + c) * kCH;
  #pragma unroll
  for (int d = 0; d < kCH; ++d) arow[d] = l[d] * inv;
}

// ---- attn @ v -> dead q/k planes (b*288 + h*27+c) ----
__global__ __launch_bounds__(256) void k_av(
    const float* __restrict__ attn, unsigned short* __restrict__ qkv_post) {
  const int h = blockIdx.y;
  const int pg = blockIdx.x * 256 + threadIdx.x;
  const int b = pg >> 16, p = pg & (kHW - 1);
  __shared__ float at[kQC * kCH];
  for (int idx = threadIdx.x; idx < kQC * kCH; idx += 256)
    at[idx] = attn[(size_t)(b * kNH + h) * kQC * kCH + idx];
  __syncthreads();
  float acc[kQC];
  #pragma unroll
  for (int c = 0; c < kQC; ++c) acc[c] = 0.f;
  for (int d = 0; d < kCH; ++d) {
    const float vv = bf2f(qkv_post[((size_t)b * kQKVC + 192 + h * kCH + d) * kHW + p]);
    #pragma unroll
    for (int c = 0; c < kQC; ++c) acc[c] += at[c * kCH + d] * vv;
  }
  #pragma unroll
  for (int c = 0; c < kQC; ++c)
    qkv_post[((size_t)b * kQKVC + h * kQC + c) * kHW + p] = f2bf(acc[c]);
}

extern "C" void kernel_launch(void* const* d_in, const int* in_sizes, int n_in,
                              void* d_out, int out_size, void* d_ws, size_t ws_size,
                              hipStream_t stream) {
  (void)in_sizes; (void)n_in;
  const float* x     = (const float*)d_in[0];
  const float* svp   = (const float*)d_in[1];
  const float* n1w   = (const float*)d_in[2];
  const float* n1b   = (const float*)d_in[3];
  const float* qkvw  = (const float*)d_in[4];
  const float* dww   = (const float*)d_in[5];
  const float* svpw  = (const float*)d_in[6];
  const float* temp  = (const float*)d_in[7];
  const float* projw = (const float*)d_in[8];
  const float* n2w   = (const float*)d_in[9];
  const float* n2b   = (const float*)d_in[10];
  const float* w1    = (const float*)d_in[11];
  const float* w2    = (const float*)d_in[12];
  const float* fw    = (const float*)d_in[13];
  float* outp = (float*)d_out;

  const size_t SZ_A = (size_t)kB * kQKVC * kHW * 2;   // 150,994,944
  const size_t SZ_C = (size_t)kB * kC * kHW * 2;      //  50,331,648
  const size_t NEED = (1u << 20) + SZ_A + SZ_C;       // 202,375,168 (proven OK)

  if (ws_size < NEED) {
    k_fill0_f32<<<(out_size + 255) / 256, 256, 0, stream>>>(outp, out_size);
    return;
  }

  char* ws = (char*)d_ws;
  float* sraw  = (float*)(ws);
  float* attn  = (float*)(ws + 65536);
  float* rnorm = (float*)(ws + 131072);
  unsigned short* A    = (unsigned short*)(ws + (1u << 20));           // qkv_post / g
  unsigned short* bufC = (unsigned short*)(ws + (1u << 20) + SZ_A);    // group out / x2
  // LN1 stats in last 2MB of A (dead before dw group 2 overwrites those planes)
  float* mu1 = (float*)(ws + (1u << 20) + SZ_A - (2u << 20));
  float* rs1 = (float*)(ws + (1u << 20) + SZ_A - (1u << 20));
  // LN2 stats after g (g ends at 133.7MB within A)
  float* mu2 = (float*)(ws + (1u << 20) + 134u * 1048576u);
  float* rs2 = (float*)(ws + (1u << 20) + 135u * 1048576u);
  unsigned short* g  = A;
  unsigned short* x2 = bufC;

  k_zero<<<(16 * 648 + 255) / 256, 256, 0, stream>>>(sraw, 16 * 648);
  k_ln1_stats<<<kNP / 256, 256, 0, stream>>>(x, mu1, rs1);
  for (int grp = 0; grp < 3; ++grp) {
    k_gemm_qkv<<<dim3(kHW / 128, kB), 256, 0, stream>>>(x, mu1, rs1, n1w, n1b, qkvw, grp, bufC);
    k_dw<<<kB * kC * 256, 256, 0, stream>>>(bufC, dww, A, grp * kC);
  }
  k_rnorm<<<816, 256, 0, stream>>>(A, svp, svpw, rnorm);
  k_qk<<<dim3(32, 16), 256, 0, stream>>>(A, svp, svpw, sraw);
  k_softmax<<<2, 256, 0, stream>>>(sraw, rnorm, temp, attn);
  k_av<<<dim3(kNP / 256, kNH), 256, 0, stream>>>(attn, A);
  k_gemm_proj<<<dim3(kHW / 128, kB), 256, 0, stream>>>(A, projw, x, x2);
  k_ln2_stats<<<kNP / 256, 256, 0, stream>>>(x2, mu2, rs2);
  k_gemm_gate<<<dim3(kHW / 128, 4, kB), 256, 0, stream>>>(x2, mu2, rs2, n2w, n2b, w1, w2, g);
  k_gemm_fout<<<dim3(kHW / 128, kB), 256, 0, stream>>>(g, fw, x2, outp);
}